// Round 1
// baseline (572.877 us; speedup 1.0000x reference)
//
#include <hip/hip_runtime.h>
#include <stdint.h>

#define NN 50000
#define NE 800000
#define DIM 256

typedef __attribute__((ext_vector_type(8))) short short8;
typedef __attribute__((ext_vector_type(4))) short short4v;
typedef __attribute__((ext_vector_type(4))) float floatx4;

__device__ __forceinline__ short f2bf(float f) {
  union { float f; uint32_t u; } v; v.f = f;
  uint32_t r = v.u + 0x7fffu + ((v.u >> 16) & 1u);
  return (short)(r >> 16);
}
__device__ __forceinline__ float bf2f(short h) {
  union { uint32_t u; float f; } v; v.u = ((uint32_t)(uint16_t)h) << 16;
  return v.f;
}

// ---------------- CSR build ----------------
__global__ __launch_bounds__(256) void k_zero(int* __restrict__ p, int n) {
  int i = blockIdx.x * 256 + threadIdx.x;
  if (i < n) p[i] = 0;
}

__global__ __launch_bounds__(256) void k_hist(const int* __restrict__ dst,
                                              int* __restrict__ hist) {
  int e = blockIdx.x * 256 + threadIdx.x;
  if (e < NE) atomicAdd(&hist[dst[e]], 1);
}

__global__ __launch_bounds__(256) void k_scan1(const int* __restrict__ hist,
                                               int* __restrict__ rowptr,
                                               int* __restrict__ bsums) {
  __shared__ int s[256];
  int i = blockIdx.x * 256 + threadIdx.x;
  int v = (i < NN) ? hist[i] : 0;
  s[threadIdx.x] = v;
  __syncthreads();
  for (int off = 1; off < 256; off <<= 1) {
    int t = (threadIdx.x >= off) ? s[threadIdx.x - off] : 0;
    __syncthreads();
    s[threadIdx.x] += t;
    __syncthreads();
  }
  if (i < NN) rowptr[i] = s[threadIdx.x] - v;  // exclusive (local)
  if (threadIdx.x == 255) bsums[blockIdx.x] = s[255];
}

__global__ __launch_bounds__(256) void k_scan2(int* __restrict__ bsums,
                                               int* __restrict__ rowptr, int nb) {
  __shared__ int s[256];
  int v = (threadIdx.x < nb) ? bsums[threadIdx.x] : 0;
  s[threadIdx.x] = v;
  __syncthreads();
  for (int off = 1; off < 256; off <<= 1) {
    int t = (threadIdx.x >= off) ? s[threadIdx.x - off] : 0;
    __syncthreads();
    s[threadIdx.x] += t;
    __syncthreads();
  }
  if (threadIdx.x < nb) bsums[threadIdx.x] = s[threadIdx.x] - v;  // exclusive
  if (threadIdx.x == 0) rowptr[NN] = NE;
}

__global__ __launch_bounds__(256) void k_scan3(const int* __restrict__ hist,
                                               int* __restrict__ rowptr,
                                               const int* __restrict__ bsums,
                                               float* __restrict__ dinv) {
  int i = blockIdx.x * 256 + threadIdx.x;
  if (i < NN) {
    rowptr[i] += bsums[blockIdx.x];
    dinv[i] = rsqrtf((float)(hist[i] + 1));  // +1 self-loop; deg >= 1 always
  }
}

__global__ __launch_bounds__(256) void k_fill(const int* __restrict__ src,
                                              const int* __restrict__ dst,
                                              const int* __restrict__ rowptr,
                                              int* __restrict__ fill,
                                              int* __restrict__ csr) {
  int e = blockIdx.x * 256 + threadIdx.x;
  if (e < NE) {
    int d = dst[e];
    int p = rowptr[d] + atomicAdd(&fill[d], 1);
    csr[p] = src[e];
  }
}

// ---------------- GEMM: C = A @ W, A fp32 [M x 256], W fp32 [256 x 256] ----------------
// Split-A bf16 (A_hi + A_lo) x bf16(W): near-fp32 accuracy, 2 MFMAs per fragment.
#define BM 128
#define BN 128
#define BK 32
#define APAD 40  // padded LDS stride in shorts

__global__ __launch_bounds__(256) void k_gemm(const float* __restrict__ A,
                                              const float* __restrict__ W,
                                              float* __restrict__ C, int M) {
  __shared__ short As_hi[BM * APAD];
  __shared__ short As_lo[BM * APAD];
  __shared__ short Bs[BN * APAD];  // stored transposed: Bs[n][k]

  const int tid = threadIdx.x;
  const int wave = tid >> 6, lane = tid & 63;
  const int wm = wave >> 1, wn = wave & 1;  // 2x2 wave grid
  const int m16 = lane & 15, q = lane >> 4;
  const int rowBase = blockIdx.x * BM;
  const int colBase = blockIdx.y * BN;

  floatx4 acc[4][4];
#pragma unroll
  for (int i = 0; i < 4; ++i)
#pragma unroll
    for (int j = 0; j < 4; ++j) acc[i][j] = (floatx4)(0.0f);

  for (int k0 = 0; k0 < DIM; k0 += BK) {
    __syncthreads();
    // --- stage A tile: 128 rows x 32 k (fp32 -> hi/lo bf16) ---
    {
      int f = tid & 7;        // which float4 in the 32-wide k chunk
      int r0 = tid >> 3;      // 32 rows per pass
#pragma unroll
      for (int p = 0; p < 4; ++p) {
        int r = r0 + p * 32;
        int grow = rowBase + r;
        float4 v;
        if (grow < M) v = *(const float4*)(A + (size_t)grow * DIM + k0 + f * 4);
        else          v = make_float4(0.f, 0.f, 0.f, 0.f);
        short4v hi, lo;
        float tmp[4] = {v.x, v.y, v.z, v.w};
#pragma unroll
        for (int u = 0; u < 4; ++u) {
          short h = f2bf(tmp[u]);
          hi[u] = h;
          lo[u] = f2bf(tmp[u] - bf2f(h));
        }
        *(short4v*)(&As_hi[r * APAD + f * 4]) = hi;
        *(short4v*)(&As_lo[r * APAD + f * 4]) = lo;
      }
    }
    // --- stage B tile: W[k0..k0+32][colBase..+128] -> Bs[n][k] (transposed) ---
    {
      int c4 = tid & 31;      // float4 along n
      int kk0 = tid >> 5;     // 8 k rows per pass
#pragma unroll
      for (int p = 0; p < 4; ++p) {
        int kk = kk0 + p * 8;
        float4 v = *(const float4*)(W + (size_t)(k0 + kk) * DIM + colBase + c4 * 4);
        Bs[(c4 * 4 + 0) * APAD + kk] = f2bf(v.x);
        Bs[(c4 * 4 + 1) * APAD + kk] = f2bf(v.y);
        Bs[(c4 * 4 + 2) * APAD + kk] = f2bf(v.z);
        Bs[(c4 * 4 + 3) * APAD + kk] = f2bf(v.w);
      }
    }
    __syncthreads();

    // --- fragments + MFMA ---
    short8 a_hi[4], a_lo[4], b[4];
#pragma unroll
    for (int i = 0; i < 4; ++i) {
      int r = wm * 64 + i * 16 + m16;
      a_hi[i] = *(const short8*)(&As_hi[r * APAD + q * 8]);
      a_lo[i] = *(const short8*)(&As_lo[r * APAD + q * 8]);
    }
#pragma unroll
    for (int j = 0; j < 4; ++j) {
      int n = wn * 64 + j * 16 + m16;
      b[j] = *(const short8*)(&Bs[n * APAD + q * 8]);
    }
#pragma unroll
    for (int i = 0; i < 4; ++i)
#pragma unroll
      for (int j = 0; j < 4; ++j) {
        acc[i][j] = __builtin_amdgcn_mfma_f32_16x16x32_bf16(a_lo[i], b[j], acc[i][j], 0, 0, 0);
        acc[i][j] = __builtin_amdgcn_mfma_f32_16x16x32_bf16(a_hi[i], b[j], acc[i][j], 0, 0, 0);
      }
  }

  // --- epilogue: C/D layout col = lane&15, row = q*4 + reg ---
#pragma unroll
  for (int i = 0; i < 4; ++i) {
#pragma unroll
    for (int reg = 0; reg < 4; ++reg) {
      int row = rowBase + wm * 64 + i * 16 + q * 4 + reg;
      if (row < M) {
#pragma unroll
        for (int j = 0; j < 4; ++j) {
          int col = colBase + wn * 64 + j * 16 + m16;
          C[(size_t)row * DIM + col] = acc[i][j][reg];
        }
      }
    }
  }
}

// ---------------- Aggregation (pull over incoming CSR) ----------------
// out[d] = post( dinv[d] * ( sum_{s in N_in(d)} g[s]*dinv[s] + g[d]*dinv[d] ) + b )
// FINAL=0: relu -> h1.  FINAL=1: out = (x + relu(.)) * 0.5
template <int FINAL>
__global__ __launch_bounds__(256) void k_agg(const float* __restrict__ g,
                                             const int* __restrict__ rowptr,
                                             const int* __restrict__ csr,
                                             const float* __restrict__ dinv,
                                             const float* __restrict__ bias,
                                             const float* __restrict__ x,
                                             float* __restrict__ out) {
  int d = blockIdx.x * 4 + (threadIdx.x >> 6);
  if (d >= NN) return;
  int lane = threadIdx.x & 63;
  int c = lane * 4;

  float dd = dinv[d];
  float4 acc = *(const float4*)(g + (size_t)d * DIM + c);
  acc.x *= dd; acc.y *= dd; acc.z *= dd; acc.w *= dd;

  int e = rowptr[d], end = rowptr[d + 1];
  for (; e + 4 <= end; e += 4) {
    int s0 = csr[e], s1 = csr[e + 1], s2 = csr[e + 2], s3 = csr[e + 3];
    float w0 = dinv[s0], w1 = dinv[s1], w2 = dinv[s2], w3 = dinv[s3];
    float4 v0 = *(const float4*)(g + (size_t)s0 * DIM + c);
    float4 v1 = *(const float4*)(g + (size_t)s1 * DIM + c);
    float4 v2 = *(const float4*)(g + (size_t)s2 * DIM + c);
    float4 v3 = *(const float4*)(g + (size_t)s3 * DIM + c);
    acc.x += v0.x * w0 + v1.x * w1 + v2.x * w2 + v3.x * w3;
    acc.y += v0.y * w0 + v1.y * w1 + v2.y * w2 + v3.y * w3;
    acc.z += v0.z * w0 + v1.z * w1 + v2.z * w2 + v3.z * w3;
    acc.w += v0.w * w0 + v1.w * w1 + v2.w * w2 + v3.w * w3;
  }
  for (; e < end; ++e) {
    int s = csr[e];
    float w = dinv[s];
    float4 v = *(const float4*)(g + (size_t)s * DIM + c);
    acc.x += v.x * w; acc.y += v.y * w; acc.z += v.z * w; acc.w += v.w * w;
  }

  float4 bv = *(const float4*)(bias + c);
  float4 r;
  r.x = fmaxf(dd * acc.x + bv.x, 0.f);
  r.y = fmaxf(dd * acc.y + bv.y, 0.f);
  r.z = fmaxf(dd * acc.z + bv.z, 0.f);
  r.w = fmaxf(dd * acc.w + bv.w, 0.f);
  if (FINAL) {
    float4 xv = *(const float4*)(x + (size_t)d * DIM + c);
    r.x = (xv.x + r.x) * 0.5f;
    r.y = (xv.y + r.y) * 0.5f;
    r.z = (xv.z + r.z) * 0.5f;
    r.w = (xv.w + r.w) * 0.5f;
  }
  *(float4*)(out + (size_t)d * DIM + c) = r;
}

// ---------------- launch ----------------
extern "C" void kernel_launch(void* const* d_in, const int* in_sizes, int n_in,
                              void* d_out, int out_size, void* d_ws, size_t ws_size,
                              hipStream_t stream) {
  const float* x  = (const float*)d_in[0];
  const int*   ei = (const int*)d_in[1];   // [2 x NE]: src row, then dst row
  const float* W1 = (const float*)d_in[2];
  const float* b1 = (const float*)d_in[3];
  const float* W2 = (const float*)d_in[4];
  const float* b2 = (const float*)d_in[5];
  float* out = (float*)d_out;

  // workspace layout (ints/floats), 16B-aligned sections
  int*   hist   = (int*)d_ws;            // NN
  int*   fill   = hist + NN;             // NN (contiguous with hist for one zero pass)
  int*   rowptr = fill + NN;             // NN+1 (padded to 50008)
  int*   bsums  = rowptr + 50008;        // 256
  int*   csr    = bsums + 256;           // NE
  float* dinv   = (float*)(csr + NE);    // NN
  float* g      = dinv + NN;             // NN*DIM  (offset 1000264 elems -> 16B aligned)
  float* h1     = g + (size_t)NN * DIM;  // NN*DIM
  // total: ~106.4 MB

  const int* esrc = ei;
  const int* edst = ei + NE;

  k_zero<<<(2 * NN + 255) / 256, 256, 0, stream>>>(hist, 2 * NN);
  k_hist<<<(NE + 255) / 256, 256, 0, stream>>>(edst, hist);
  k_scan1<<<196, 256, 0, stream>>>(hist, rowptr, bsums);
  k_scan2<<<1, 256, 0, stream>>>(bsums, rowptr, 196);
  k_scan3<<<196, 256, 0, stream>>>(hist, rowptr, bsums, dinv);
  k_fill<<<(NE + 255) / 256, 256, 0, stream>>>(esrc, edst, rowptr, fill, csr);

  dim3 ggrid((NN + BM - 1) / BM, DIM / BN);
  k_gemm<<<ggrid, 256, 0, stream>>>(x, W1, g, NN);
  k_agg<0><<<NN / 4, 256, 0, stream>>>(g, rowptr, csr, dinv, b1, nullptr, h1);
  k_gemm<<<ggrid, 256, 0, stream>>>(h1, W2, g, NN);
  k_agg<1><<<NN / 4, 256, 0, stream>>>(g, rowptr, csr, dinv, b2, x, out);
}

// Round 3
// 438.309 us; speedup vs baseline: 1.3070x; 1.3070x over previous
//
#include <hip/hip_runtime.h>
#include <stdint.h>

#define NN 50000
#define NE 800000
#define DIM 256

typedef __attribute__((ext_vector_type(8))) short short8;
typedef __attribute__((ext_vector_type(4))) short short4v;
typedef __attribute__((ext_vector_type(4))) unsigned short ushort4v;
typedef __attribute__((ext_vector_type(8))) unsigned short ushort8v;
typedef __attribute__((ext_vector_type(4))) float floatx4;

__device__ __forceinline__ uint16_t f2bf(float f) {
  union { float f; uint32_t u; } v; v.f = f;
  uint32_t r = v.u + 0x7fffu + ((v.u >> 16) & 1u);
  return (uint16_t)(r >> 16);
}
__device__ __forceinline__ float bf2f(uint16_t h) {
  union { uint32_t u; float f; } v; v.u = ((uint32_t)h) << 16;
  return v.f;
}

// ---------------- CSR build ----------------
__global__ __launch_bounds__(256) void k_zero(int* __restrict__ p, int n) {
  int i = blockIdx.x * 256 + threadIdx.x;
  if (i < n) p[i] = 0;
}

__global__ __launch_bounds__(256) void k_hist(const int* __restrict__ dst,
                                              int* __restrict__ hist) {
  int e = blockIdx.x * 256 + threadIdx.x;
  if (e < NE) atomicAdd(&hist[dst[e]], 1);
}

__global__ __launch_bounds__(256) void k_scan1(const int* __restrict__ hist,
                                               int* __restrict__ rowptr,
                                               int* __restrict__ bsums) {
  __shared__ int s[256];
  int i = blockIdx.x * 256 + threadIdx.x;
  int v = (i < NN) ? hist[i] : 0;
  s[threadIdx.x] = v;
  __syncthreads();
  for (int off = 1; off < 256; off <<= 1) {
    int t = (threadIdx.x >= off) ? s[threadIdx.x - off] : 0;
    __syncthreads();
    s[threadIdx.x] += t;
    __syncthreads();
  }
  if (i < NN) rowptr[i] = s[threadIdx.x] - v;  // exclusive (local)
  if (threadIdx.x == 255) bsums[blockIdx.x] = s[255];
}

__global__ __launch_bounds__(256) void k_scan2(int* __restrict__ bsums,
                                               int* __restrict__ rowptr, int nb) {
  __shared__ int s[256];
  int v = (threadIdx.x < nb) ? bsums[threadIdx.x] : 0;
  s[threadIdx.x] = v;
  __syncthreads();
  for (int off = 1; off < 256; off <<= 1) {
    int t = (threadIdx.x >= off) ? s[threadIdx.x - off] : 0;
    __syncthreads();
    s[threadIdx.x] += t;
    __syncthreads();
  }
  if (threadIdx.x < nb) bsums[threadIdx.x] = s[threadIdx.x] - v;  // exclusive
  if (threadIdx.x == 0) rowptr[NN] = NE;
}

__global__ __launch_bounds__(256) void k_scan3(const int* __restrict__ hist,
                                               int* __restrict__ rowptr,
                                               const int* __restrict__ bsums,
                                               float* __restrict__ dinv) {
  int i = blockIdx.x * 256 + threadIdx.x;
  if (i < NN) {
    rowptr[i] += bsums[blockIdx.x];
    dinv[i] = rsqrtf((float)(hist[i] + 1));  // +1 self-loop; deg >= 1 always
  }
}

__global__ __launch_bounds__(256) void k_fill(const int* __restrict__ src,
                                              const int* __restrict__ dst,
                                              const int* __restrict__ rowptr,
                                              int* __restrict__ fill,
                                              int* __restrict__ csr) {
  int e = blockIdx.x * 256 + threadIdx.x;
  if (e < NE) {
    int d = dst[e];
    int p = rowptr[d] + atomicAdd(&fill[d], 1);
    csr[p] = src[e];
  }
}

// ---------------- GEMM tiles ----------------
#define BM 128
#define BN 128
#define BK 32
#define APAD 40  // padded LDS stride in shorts

// C(bf16) = A(fp32) @ W(fp32), split-A (hi+lo bf16) for near-fp32 accuracy.
__global__ __launch_bounds__(256) void k_gemm_f32(const float* __restrict__ A,
                                                  const float* __restrict__ W,
                                                  uint16_t* __restrict__ C, int M) {
  __shared__ short As_hi[BM * APAD];
  __shared__ short As_lo[BM * APAD];
  __shared__ short Bs[BN * APAD];  // transposed: Bs[n][k]

  const int tid = threadIdx.x;
  const int wave = tid >> 6, lane = tid & 63;
  const int wm = wave >> 1, wn = wave & 1;
  const int m16 = lane & 15, q = lane >> 4;
  const int rowBase = blockIdx.x * BM;
  const int colBase = blockIdx.y * BN;

  floatx4 acc[4][4];
#pragma unroll
  for (int i = 0; i < 4; ++i)
#pragma unroll
    for (int j = 0; j < 4; ++j) acc[i][j] = (floatx4)(0.0f);

  for (int k0 = 0; k0 < DIM; k0 += BK) {
    __syncthreads();
    {  // stage A: 128 rows x 32 k, fp32 -> hi/lo bf16
      int f = tid & 7;
      int r0 = tid >> 3;
#pragma unroll
      for (int p = 0; p < 4; ++p) {
        int r = r0 + p * 32;
        int grow = rowBase + r;
        float4 v;
        if (grow < M) v = *(const float4*)(A + (size_t)grow * DIM + k0 + f * 4);
        else          v = make_float4(0.f, 0.f, 0.f, 0.f);
        short4v hi, lo;
        float tmp[4] = {v.x, v.y, v.z, v.w};
#pragma unroll
        for (int u = 0; u < 4; ++u) {
          uint16_t h = f2bf(tmp[u]);
          hi[u] = (short)h;
          lo[u] = (short)f2bf(tmp[u] - bf2f(h));
        }
        *(short4v*)(&As_hi[r * APAD + f * 4]) = hi;
        *(short4v*)(&As_lo[r * APAD + f * 4]) = lo;
      }
    }
    {  // stage B: W[k0..+32][colBase..+128] -> Bs[n][k]
      int c4 = tid & 31;
      int kk0 = tid >> 5;
#pragma unroll
      for (int p = 0; p < 4; ++p) {
        int kk = kk0 + p * 8;
        float4 v = *(const float4*)(W + (size_t)(k0 + kk) * DIM + colBase + c4 * 4);
        Bs[(c4 * 4 + 0) * APAD + kk] = (short)f2bf(v.x);
        Bs[(c4 * 4 + 1) * APAD + kk] = (short)f2bf(v.y);
        Bs[(c4 * 4 + 2) * APAD + kk] = (short)f2bf(v.z);
        Bs[(c4 * 4 + 3) * APAD + kk] = (short)f2bf(v.w);
      }
    }
    __syncthreads();

    short8 a_hi[4], a_lo[4], b[4];
#pragma unroll
    for (int i = 0; i < 4; ++i) {
      int r = wm * 64 + i * 16 + m16;
      a_hi[i] = *(const short8*)(&As_hi[r * APAD + q * 8]);
      a_lo[i] = *(const short8*)(&As_lo[r * APAD + q * 8]);
    }
#pragma unroll
    for (int j = 0; j < 4; ++j) {
      int n = wn * 64 + j * 16 + m16;
      b[j] = *(const short8*)(&Bs[n * APAD + q * 8]);
    }
#pragma unroll
    for (int i = 0; i < 4; ++i)
#pragma unroll
      for (int j = 0; j < 4; ++j) {
        acc[i][j] = __builtin_amdgcn_mfma_f32_16x16x32_bf16(a_lo[i], b[j], acc[i][j], 0, 0, 0);
        acc[i][j] = __builtin_amdgcn_mfma_f32_16x16x32_bf16(a_hi[i], b[j], acc[i][j], 0, 0, 0);
      }
  }

#pragma unroll
  for (int i = 0; i < 4; ++i) {
#pragma unroll
    for (int reg = 0; reg < 4; ++reg) {
      int row = rowBase + wm * 64 + i * 16 + q * 4 + reg;
      if (row < M) {
#pragma unroll
        for (int j = 0; j < 4; ++j) {
          int col = colBase + wn * 64 + j * 16 + m16;
          C[(size_t)row * DIM + col] = f2bf(acc[i][j][reg]);
        }
      }
    }
  }
}

// C(bf16) = A(bf16) @ W(fp32): direct bf16 A staging, single MFMA per fragment.
__global__ __launch_bounds__(256) void k_gemm_bf(const uint16_t* __restrict__ A,
                                                 const float* __restrict__ W,
                                                 uint16_t* __restrict__ C, int M) {
  __shared__ short As[BM * APAD];
  __shared__ short Bs[BN * APAD];  // transposed: Bs[n][k]

  const int tid = threadIdx.x;
  const int wave = tid >> 6, lane = tid & 63;
  const int wm = wave >> 1, wn = wave & 1;
  const int m16 = lane & 15, q = lane >> 4;
  const int rowBase = blockIdx.x * BM;
  const int colBase = blockIdx.y * BN;

  floatx4 acc[4][4];
#pragma unroll
  for (int i = 0; i < 4; ++i)
#pragma unroll
    for (int j = 0; j < 4; ++j) acc[i][j] = (floatx4)(0.0f);

  for (int k0 = 0; k0 < DIM; k0 += BK) {
    __syncthreads();
    {  // stage A: 128 rows x 32 k bf16, 16B vector copies
      int f = tid & 3;       // which 8-short chunk of the 32-k row
      int r0 = tid >> 2;     // 64 rows per pass
#pragma unroll
      for (int p = 0; p < 2; ++p) {
        int r = r0 + p * 64;
        int grow = rowBase + r;
        ushort8v v;
        if (grow < M) v = *(const ushort8v*)(A + (size_t)grow * DIM + k0 + f * 8);
        else          v = (ushort8v)(0);
        *(ushort8v*)((unsigned short*)&As[r * APAD + f * 8]) = v;
      }
    }
    {  // stage B: W[k0..+32][colBase..+128] -> Bs[n][k]
      int c4 = tid & 31;
      int kk0 = tid >> 5;
#pragma unroll
      for (int p = 0; p < 4; ++p) {
        int kk = kk0 + p * 8;
        float4 v = *(const float4*)(W + (size_t)(k0 + kk) * DIM + colBase + c4 * 4);
        Bs[(c4 * 4 + 0) * APAD + kk] = (short)f2bf(v.x);
        Bs[(c4 * 4 + 1) * APAD + kk] = (short)f2bf(v.y);
        Bs[(c4 * 4 + 2) * APAD + kk] = (short)f2bf(v.z);
        Bs[(c4 * 4 + 3) * APAD + kk] = (short)f2bf(v.w);
      }
    }
    __syncthreads();

    short8 a[4], b[4];
#pragma unroll
    for (int i = 0; i < 4; ++i) {
      int r = wm * 64 + i * 16 + m16;
      a[i] = *(const short8*)(&As[r * APAD + q * 8]);
    }
#pragma unroll
    for (int j = 0; j < 4; ++j) {
      int n = wn * 64 + j * 16 + m16;
      b[j] = *(const short8*)(&Bs[n * APAD + q * 8]);
    }
#pragma unroll
    for (int i = 0; i < 4; ++i)
#pragma unroll
      for (int j = 0; j < 4; ++j)
        acc[i][j] = __builtin_amdgcn_mfma_f32_16x16x32_bf16(a[i], b[j], acc[i][j], 0, 0, 0);
  }

#pragma unroll
  for (int i = 0; i < 4; ++i) {
#pragma unroll
    for (int reg = 0; reg < 4; ++reg) {
      int row = rowBase + wm * 64 + i * 16 + q * 4 + reg;
      if (row < M) {
#pragma unroll
        for (int j = 0; j < 4; ++j) {
          int col = colBase + wn * 64 + j * 16 + m16;
          C[(size_t)row * DIM + col] = f2bf(acc[i][j][reg]);
        }
      }
    }
  }
}

// ---------------- Aggregation (pull over incoming CSR, bf16 gather) ----------------
// out[d] = post( dinv[d] * ( sum_{s in N_in(d)} g[s]*dinv[s] + g[d]*dinv[d] ) + b )
// FINAL=0: relu -> h1 (bf16).  FINAL=1: out = (x + relu(.)) * 0.5 (fp32)
template <int FINAL>
__global__ __launch_bounds__(256) void k_agg(const uint16_t* __restrict__ g,
                                             const int* __restrict__ rowptr,
                                             const int* __restrict__ csr,
                                             const float* __restrict__ dinv,
                                             const float* __restrict__ bias,
                                             const float* __restrict__ x,
                                             uint16_t* __restrict__ outb,
                                             float* __restrict__ outf) {
  int d = blockIdx.x * 4 + (threadIdx.x >> 6);
  if (d >= NN) return;
  int lane = threadIdx.x & 63;
  int c = lane * 4;

  float dd = dinv[d];
  ushort4v u = *(const ushort4v*)(g + (size_t)d * DIM + c);
  float4 acc;
  acc.x = bf2f(u[0]) * dd;
  acc.y = bf2f(u[1]) * dd;
  acc.z = bf2f(u[2]) * dd;
  acc.w = bf2f(u[3]) * dd;

  int e = rowptr[d], end = rowptr[d + 1];
  for (; e + 4 <= end; e += 4) {
    int s0 = csr[e], s1 = csr[e + 1], s2 = csr[e + 2], s3 = csr[e + 3];
    float w0 = dinv[s0], w1 = dinv[s1], w2 = dinv[s2], w3 = dinv[s3];
    ushort4v v0 = *(const ushort4v*)(g + (size_t)s0 * DIM + c);
    ushort4v v1 = *(const ushort4v*)(g + (size_t)s1 * DIM + c);
    ushort4v v2 = *(const ushort4v*)(g + (size_t)s2 * DIM + c);
    ushort4v v3 = *(const ushort4v*)(g + (size_t)s3 * DIM + c);
    acc.x += bf2f(v0[0]) * w0 + bf2f(v1[0]) * w1 + bf2f(v2[0]) * w2 + bf2f(v3[0]) * w3;
    acc.y += bf2f(v0[1]) * w0 + bf2f(v1[1]) * w1 + bf2f(v2[1]) * w2 + bf2f(v3[1]) * w3;
    acc.z += bf2f(v0[2]) * w0 + bf2f(v1[2]) * w1 + bf2f(v2[2]) * w2 + bf2f(v3[2]) * w3;
    acc.w += bf2f(v0[3]) * w0 + bf2f(v1[3]) * w1 + bf2f(v2[3]) * w2 + bf2f(v3[3]) * w3;
  }
  for (; e < end; ++e) {
    int s = csr[e];
    float w = dinv[s];
    ushort4v v = *(const ushort4v*)(g + (size_t)s * DIM + c);
    acc.x += bf2f(v[0]) * w;
    acc.y += bf2f(v[1]) * w;
    acc.z += bf2f(v[2]) * w;
    acc.w += bf2f(v[3]) * w;
  }

  float4 bv = *(const float4*)(bias + c);
  float4 r;
  r.x = fmaxf(dd * acc.x + bv.x, 0.f);
  r.y = fmaxf(dd * acc.y + bv.y, 0.f);
  r.z = fmaxf(dd * acc.z + bv.z, 0.f);
  r.w = fmaxf(dd * acc.w + bv.w, 0.f);
  if (FINAL) {
    float4 xv = *(const float4*)(x + (size_t)d * DIM + c);
    r.x = (xv.x + r.x) * 0.5f;
    r.y = (xv.y + r.y) * 0.5f;
    r.z = (xv.z + r.z) * 0.5f;
    r.w = (xv.w + r.w) * 0.5f;
    *(float4*)(outf + (size_t)d * DIM + c) = r;
  } else {
    ushort4v o;
    o[0] = f2bf(r.x); o[1] = f2bf(r.y); o[2] = f2bf(r.z); o[3] = f2bf(r.w);
    *(ushort4v*)(outb + (size_t)d * DIM + c) = o;
  }
}

// ---------------- launch ----------------
extern "C" void kernel_launch(void* const* d_in, const int* in_sizes, int n_in,
                              void* d_out, int out_size, void* d_ws, size_t ws_size,
                              hipStream_t stream) {
  const float* x  = (const float*)d_in[0];
  const int*   ei = (const int*)d_in[1];   // [2 x NE]: src row, then dst row
  const float* W1 = (const float*)d_in[2];
  const float* b1 = (const float*)d_in[3];
  const float* W2 = (const float*)d_in[4];
  const float* b2 = (const float*)d_in[5];
  float* out = (float*)d_out;

  int*      hist   = (int*)d_ws;             // NN
  int*      fill   = hist + NN;              // NN
  int*      rowptr = fill + NN;              // NN+1 (padded to 50008)
  int*      bsums  = rowptr + 50008;         // 256
  int*      csr    = bsums + 256;            // NE
  float*    dinv   = (float*)(csr + NE);     // NN
  uint16_t* g      = (uint16_t*)(dinv + NN); // NN*DIM bf16 (16B-aligned)
  uint16_t* h1     = g + (size_t)NN * DIM;   // NN*DIM bf16

  const int* esrc = ei;
  const int* edst = ei + NE;

  k_zero<<<(2 * NN + 255) / 256, 256, 0, stream>>>(hist, 2 * NN);
  k_hist<<<(NE + 255) / 256, 256, 0, stream>>>(edst, hist);
  k_scan1<<<196, 256, 0, stream>>>(hist, rowptr, bsums);
  k_scan2<<<1, 256, 0, stream>>>(bsums, rowptr, 196);
  k_scan3<<<196, 256, 0, stream>>>(hist, rowptr, bsums, dinv);
  k_fill<<<(NE + 255) / 256, 256, 0, stream>>>(esrc, edst, rowptr, fill, csr);

  dim3 ggrid((NN + BM - 1) / BM, DIM / BN);
  k_gemm_f32<<<ggrid, 256, 0, stream>>>(x, W1, g, NN);
  k_agg<0><<<NN / 4, 256, 0, stream>>>(g, rowptr, csr, dinv, b1, nullptr, h1, nullptr);
  k_gemm_bf<<<ggrid, 256, 0, stream>>>(h1, W2, g, NN);
  k_agg<1><<<NN / 4, 256, 0, stream>>>(g, rowptr, csr, dinv, b2, x, nullptr, out);
}

// Round 4
// 417.736 us; speedup vs baseline: 1.3714x; 1.0492x over previous
//
#include <hip/hip_runtime.h>
#include <stdint.h>

#define NN 50000
#define NPAD 50048   // padded row count so 128-row GEMM tiles never read OOB
#define NE 800000
#define DIM 256

typedef __attribute__((ext_vector_type(8))) short short8;
typedef __attribute__((ext_vector_type(4))) unsigned short ushort4v;
typedef __attribute__((ext_vector_type(8))) unsigned short ushort8v;
typedef __attribute__((ext_vector_type(4))) float floatx4;

__device__ __forceinline__ uint16_t f2bf(float f) {
  union { float f; uint32_t u; } v; v.f = f;
  uint32_t r = v.u + 0x7fffu + ((v.u >> 16) & 1u);
  return (uint16_t)(r >> 16);
}
__device__ __forceinline__ float bf2f(uint16_t h) {
  union { uint32_t u; float f; } v; v.u = ((uint32_t)h) << 16;
  return v.f;
}

// async global->LDS, 16B per lane; dest = wave-uniform base + lane*16
__device__ __forceinline__ void stage16(const uint16_t* gp, short* lbase, int lane) {
#if __has_builtin(__builtin_amdgcn_global_load_lds)
  __builtin_amdgcn_global_load_lds((__attribute__((address_space(1))) void*)gp,
                                   (__attribute__((address_space(3))) void*)lbase,
                                   16, 0, 0);
#else
  *(ushort8v*)((uint16_t*)lbase + lane * 8) = *(const ushort8v*)gp;
#endif
}

// ---------------- CSR build ----------------
__global__ __launch_bounds__(256) void k_zero(int* __restrict__ p, int n) {
  int i = blockIdx.x * 256 + threadIdx.x;
  if (i < n) p[i] = 0;
}

__global__ __launch_bounds__(256) void k_hist(const int* __restrict__ dst,
                                              int* __restrict__ hist) {
  int e = blockIdx.x * 256 + threadIdx.x;
  if (e < NE) atomicAdd(&hist[dst[e]], 1);
}

__global__ __launch_bounds__(256) void k_scan1(const int* __restrict__ hist,
                                               int* __restrict__ rowptr,
                                               int* __restrict__ bsums) {
  __shared__ int s[256];
  int i = blockIdx.x * 256 + threadIdx.x;
  int v = (i < NN) ? hist[i] : 0;
  s[threadIdx.x] = v;
  __syncthreads();
  for (int off = 1; off < 256; off <<= 1) {
    int t = (threadIdx.x >= off) ? s[threadIdx.x - off] : 0;
    __syncthreads();
    s[threadIdx.x] += t;
    __syncthreads();
  }
  if (i < NN) rowptr[i] = s[threadIdx.x] - v;  // exclusive (local)
  if (threadIdx.x == 255) bsums[blockIdx.x] = s[255];
}

__global__ __launch_bounds__(256) void k_scan2(int* __restrict__ bsums,
                                               int* __restrict__ rowptr, int nb) {
  __shared__ int s[256];
  int v = (threadIdx.x < nb) ? bsums[threadIdx.x] : 0;
  s[threadIdx.x] = v;
  __syncthreads();
  for (int off = 1; off < 256; off <<= 1) {
    int t = (threadIdx.x >= off) ? s[threadIdx.x - off] : 0;
    __syncthreads();
    s[threadIdx.x] += t;
    __syncthreads();
  }
  if (threadIdx.x < nb) bsums[threadIdx.x] = s[threadIdx.x] - v;  // exclusive
  if (threadIdx.x == 0) rowptr[NN] = NE;
}

__global__ __launch_bounds__(256) void k_scan3(const int* __restrict__ hist,
                                               int* __restrict__ rowptr,
                                               const int* __restrict__ bsums,
                                               float* __restrict__ dinv) {
  int i = blockIdx.x * 256 + threadIdx.x;
  if (i < NN) {
    rowptr[i] += bsums[blockIdx.x];
    dinv[i] = rsqrtf((float)(hist[i] + 1));  // +1 self-loop; deg >= 1 always
  }
}

__global__ __launch_bounds__(256) void k_fill(const int* __restrict__ src,
                                              const int* __restrict__ dst,
                                              const int* __restrict__ rowptr,
                                              int* __restrict__ fill,
                                              int* __restrict__ csr) {
  int e = blockIdx.x * 256 + threadIdx.x;
  if (e < NE) {
    int d = dst[e];
    int p = rowptr[d] + atomicAdd(&fill[d], 1);
    csr[p] = src[e];
  }
}

// ---------------- prep: W (fp32 [k][n]) -> Wt (bf16 [n][k]) ----------------
__global__ __launch_bounds__(256) void k_prep_w(const float* __restrict__ W,
                                                uint16_t* __restrict__ Wt) {
  __shared__ float t[32][33];
  int bx = blockIdx.x & 7, by = blockIdx.x >> 3;
  int tx = threadIdx.x & 31, ty = threadIdx.x >> 5;  // 32 x 8
#pragma unroll
  for (int p = 0; p < 4; ++p)
    t[ty + p * 8][tx] = W[(size_t)(by * 32 + ty + p * 8) * 256 + bx * 32 + tx];
  __syncthreads();
#pragma unroll
  for (int p = 0; p < 4; ++p)
    Wt[(size_t)(bx * 32 + ty + p * 8) * 256 + by * 32 + tx] = f2bf(t[tx][ty + p * 8]);
}

// ---------------- prep: x fp32 -> hi/lo bf16 (exact split) ----------------
__global__ __launch_bounds__(256) void k_split(const float* __restrict__ x,
                                               uint16_t* __restrict__ hi,
                                               uint16_t* __restrict__ lo) {
  size_t i = (size_t)(blockIdx.x * 256 + threadIdx.x) * 4;  // 12.8M floats total
  float4 v = *(const float4*)(x + i);
  float a[4] = {v.x, v.y, v.z, v.w};
  ushort4v h, l;
#pragma unroll
  for (int u = 0; u < 4; ++u) {
    uint16_t hh = f2bf(a[u]);
    h[u] = hh;
    l[u] = f2bf(a[u] - bf2f(hh));
  }
  *(ushort4v*)(hi + i) = h;
  *(ushort4v*)(lo + i) = l;
}

// ---------------- GEMM (m97-style): C(bf16) = (Ah [+ Al]) @ Wt^T ----------------
// Ah/Al: bf16 [NPAD][256] row-major; Wt: bf16 [256 n][256 k]; C: bf16 [NPAD][256]
#define BM 128
#define BN 128
#define BK 32

template <int SPLIT>
__global__ __launch_bounds__(256) void k_gemm(const uint16_t* __restrict__ Ah,
                                              const uint16_t* __restrict__ Al,
                                              const uint16_t* __restrict__ Wt,
                                              uint16_t* __restrict__ C, int M) {
  __shared__ short Ash[BM * BK];
  __shared__ short Asl[BM * BK];
  __shared__ short Bs[BN * BK];

  const int tid = threadIdx.x;
  const int wave = tid >> 6, lane = tid & 63;
  const int wm = wave >> 1, wn = wave & 1;
  const int m16 = lane & 15, q = lane >> 4;
  const int rowBase = blockIdx.x * BM;
  const int colBase = blockIdx.y * BN;
  const int rsub = lane >> 2;          // 0..15
  const int kch = (lane & 3) * 8;      // bf16-elem offset within BK chunk

  floatx4 acc[4][4];
#pragma unroll
  for (int i = 0; i < 4; ++i)
#pragma unroll
    for (int j = 0; j < 4; ++j) acc[i][j] = (floatx4)(0.0f);

  for (int k0 = 0; k0 < DIM; k0 += BK) {
    __syncthreads();
    // stage: each wave covers 16 rows per pass; lane l -> (row l>>2, 16B chunk l&3)
#pragma unroll
    for (int p = 0; p < 2; ++p) {
      int rb = wave * 16 + p * 64;
      stage16(Ah + (size_t)(rowBase + rb + rsub) * DIM + k0 + kch, &Ash[rb * BK], lane);
      if (SPLIT)
        stage16(Al + (size_t)(rowBase + rb + rsub) * DIM + k0 + kch, &Asl[rb * BK], lane);
      stage16(Wt + (size_t)(colBase + rb + rsub) * DIM + k0 + kch, &Bs[rb * BK], lane);
    }
    __syncthreads();

    short8 ah[4], al[4], b[4];
#pragma unroll
    for (int i = 0; i < 4; ++i) {
      int r = wm * 64 + i * 16 + m16;
      ah[i] = *(const short8*)(&Ash[r * BK + q * 8]);
      if (SPLIT) al[i] = *(const short8*)(&Asl[r * BK + q * 8]);
    }
#pragma unroll
    for (int j = 0; j < 4; ++j) {
      int n = wn * 64 + j * 16 + m16;
      b[j] = *(const short8*)(&Bs[n * BK + q * 8]);
    }
#pragma unroll
    for (int i = 0; i < 4; ++i)
#pragma unroll
      for (int j = 0; j < 4; ++j) {
        if (SPLIT)
          acc[i][j] = __builtin_amdgcn_mfma_f32_16x16x32_bf16(al[i], b[j], acc[i][j], 0, 0, 0);
        acc[i][j] = __builtin_amdgcn_mfma_f32_16x16x32_bf16(ah[i], b[j], acc[i][j], 0, 0, 0);
      }
  }

  // epilogue: C/D layout col = lane&15, row = q*4 + reg  (verified)
#pragma unroll
  for (int i = 0; i < 4; ++i) {
#pragma unroll
    for (int reg = 0; reg < 4; ++reg) {
      int row = rowBase + wm * 64 + i * 16 + q * 4 + reg;
      if (row < M) {
#pragma unroll
        for (int j = 0; j < 4; ++j) {
          int col = colBase + wn * 64 + j * 16 + m16;
          C[(size_t)row * DIM + col] = f2bf(acc[i][j][reg]);
        }
      }
    }
  }
}

// ---------------- Aggregation: paired-edge pull over incoming CSR ----------------
// lanes 0-31: edge e (16B/lane), lanes 32-63: edge e+1; cross-half shfl reduce.
// out[d] = post( dinv[d] * ( sum_s g[s]*dinv[s] + g[d]*dinv[d] ) + b )
template <int FINAL>
__global__ __launch_bounds__(256) void k_agg(const uint16_t* __restrict__ g,
                                             const int* __restrict__ rowptr,
                                             const int* __restrict__ csr,
                                             const float* __restrict__ dinv,
                                             const float* __restrict__ bias,
                                             const float* __restrict__ x,
                                             uint16_t* __restrict__ outb,
                                             float* __restrict__ outf) {
  int d = blockIdx.x * 4 + (threadIdx.x >> 6);
  int lane = threadIdx.x & 63;
  int half = lane >> 5, li = lane & 31;
  int c = li * 8;  // 8 feats (16 B) per lane

  float dd = dinv[d];
  float acc[8];
  {
    ushort8v u = *(const ushort8v*)(g + (size_t)d * DIM + c);
    float wd = half ? 0.f : dd;
#pragma unroll
    for (int t = 0; t < 8; ++t) acc[t] = bf2f(u[t]) * wd;
  }

  int e = rowptr[d] + half, end = rowptr[d + 1];
  for (; e + 2 < end; e += 4) {  // each half: 2 edges/iter -> 4 edges/wave/iter
    int s0 = csr[e], s1 = csr[e + 2];
    float w0 = dinv[s0], w1 = dinv[s1];
    ushort8v v0 = *(const ushort8v*)(g + (size_t)s0 * DIM + c);
    ushort8v v1 = *(const ushort8v*)(g + (size_t)s1 * DIM + c);
#pragma unroll
    for (int t = 0; t < 8; ++t) acc[t] += bf2f(v0[t]) * w0 + bf2f(v1[t]) * w1;
  }
  if (e < end) {
    int s = csr[e];
    float w = dinv[s];
    ushort8v v = *(const ushort8v*)(g + (size_t)s * DIM + c);
#pragma unroll
    for (int t = 0; t < 8; ++t) acc[t] += bf2f(v[t]) * w;
  }

  // combine halves: lane i += lane i+32
#pragma unroll
  for (int t = 0; t < 8; ++t) acc[t] += __shfl_down(acc[t], 32);

  if (half == 0) {
    float4 b0 = *(const float4*)(bias + c);
    float4 b1 = *(const float4*)(bias + c + 4);
    float bb[8] = {b0.x, b0.y, b0.z, b0.w, b1.x, b1.y, b1.z, b1.w};
    float r[8];
#pragma unroll
    for (int t = 0; t < 8; ++t) r[t] = fmaxf(dd * acc[t] + bb[t], 0.f);
    if (FINAL) {
      float4 x0 = *(const float4*)(x + (size_t)d * DIM + c);
      float4 x1 = *(const float4*)(x + (size_t)d * DIM + c + 4);
      float xx[8] = {x0.x, x0.y, x0.z, x0.w, x1.x, x1.y, x1.z, x1.w};
      float4 o0, o1;
      o0.x = (xx[0] + r[0]) * 0.5f; o0.y = (xx[1] + r[1]) * 0.5f;
      o0.z = (xx[2] + r[2]) * 0.5f; o0.w = (xx[3] + r[3]) * 0.5f;
      o1.x = (xx[4] + r[4]) * 0.5f; o1.y = (xx[5] + r[5]) * 0.5f;
      o1.z = (xx[6] + r[6]) * 0.5f; o1.w = (xx[7] + r[7]) * 0.5f;
      *(float4*)(outf + (size_t)d * DIM + c) = o0;
      *(float4*)(outf + (size_t)d * DIM + c + 4) = o1;
    } else {
      ushort8v o;
#pragma unroll
      for (int t = 0; t < 8; ++t) o[t] = f2bf(r[t]);
      *(ushort8v*)(outb + (size_t)d * DIM + c) = o;
    }
  }
}

// ---------------- launch ----------------
extern "C" void kernel_launch(void* const* d_in, const int* in_sizes, int n_in,
                              void* d_out, int out_size, void* d_ws, size_t ws_size,
                              hipStream_t stream) {
  const float* x  = (const float*)d_in[0];
  const int*   ei = (const int*)d_in[1];   // [2 x NE]: src row, then dst row
  const float* W1 = (const float*)d_in[2];
  const float* b1 = (const float*)d_in[3];
  const float* W2 = (const float*)d_in[4];
  const float* b2 = (const float*)d_in[5];
  float* out = (float*)d_out;

  // workspace layout (all bf16 arrays 16B-aligned)
  int*      hist   = (int*)d_ws;               // NN
  int*      fill   = hist + NN;                // NN
  int*      rowptr = fill + NN;                // NN+1 (padded to 50008)
  int*      bsums  = rowptr + 50008;           // 256
  int*      csr    = bsums + 256;              // NE
  float*    dinv   = (float*)(csr + NE);       // NN
  uint16_t* Wt1    = (uint16_t*)(dinv + NN);   // 256*256
  uint16_t* Wt2    = Wt1 + 256 * 256;          // 256*256
  uint16_t* x_hi   = Wt2 + 256 * 256;          // NPAD*DIM
  uint16_t* x_lo   = x_hi + (size_t)NPAD * DIM;
  uint16_t* g      = x_lo + (size_t)NPAD * DIM;
  uint16_t* h1     = g + (size_t)NPAD * DIM;   // total ~107.0 MB

  const int* esrc = ei;
  const int* edst = ei + NE;

  k_zero<<<(2 * NN + 255) / 256, 256, 0, stream>>>(hist, 2 * NN);
  k_hist<<<(NE + 255) / 256, 256, 0, stream>>>(edst, hist);
  k_scan1<<<196, 256, 0, stream>>>(hist, rowptr, bsums);
  k_scan2<<<1, 256, 0, stream>>>(bsums, rowptr, 196);
  k_scan3<<<196, 256, 0, stream>>>(hist, rowptr, bsums, dinv);
  k_fill<<<(NE + 255) / 256, 256, 0, stream>>>(esrc, edst, rowptr, fill, csr);

  k_prep_w<<<64, 256, 0, stream>>>(W1, Wt1);
  k_prep_w<<<64, 256, 0, stream>>>(W2, Wt2);
  k_split<<<12500, 256, 0, stream>>>(x, x_hi, x_lo);  // 12.8M floats / 4 / 256

  dim3 ggrid((NN + BM - 1) / BM, DIM / BN);
  k_gemm<1><<<ggrid, 256, 0, stream>>>(x_hi, x_lo, Wt1, g, NN);
  k_agg<0><<<NN / 4, 256, 0, stream>>>(g, rowptr, csr, dinv, b1, nullptr, h1, nullptr);
  k_gemm<0><<<ggrid, 256, 0, stream>>>(h1, nullptr, Wt2, g, NN);
  k_agg<1><<<NN / 4, 256, 0, stream>>>(g, rowptr, csr, dinv, b2, x, nullptr, out);
}